// Round 1
// baseline (3030.479 us; speedup 1.0000x reference)
//
#include <hip/hip_runtime.h>
#include <stdint.h>
#include <math.h>
#include <limits.h>

// Batched autoregressive LSTM decode, B=32 S=48 V=32000 E=H=512.
// Strategy: per-step kernels (cell -> logits+partials -> finalize), raw logits
// written to d_out, one final pass applies log-softmax + active mask.
// RNG: JAX threefry, PARTITIONABLE semantics (JAX >= 0.4.36 default).
// If validation shows wrong tokens from step 0, flip JAX_PARTITIONABLE to 0.

#define SEQ 48
#define BSZ 32
#define VOC 32000
#define EDIM 512
#define HDIM 512
#define GDIM 2048   // 4*H
#define KTOT 1024   // E + H
#define EOS_TOK (VOC - 2)

#define JAX_PARTITIONABLE 1

__device__ __forceinline__ void threefry2x32(uint32_t k0, uint32_t k1,
                                             uint32_t x0, uint32_t x1,
                                             uint32_t& o0, uint32_t& o1)
{
  uint32_t ks2 = k0 ^ k1 ^ 0x1BD11BDAu;
  x0 += k0; x1 += k1;
#define TFR(r) x0 += x1; x1 = (x1 << (r)) | (x1 >> (32 - (r))); x1 ^= x0;
  TFR(13) TFR(15) TFR(26) TFR(6)
  x0 += k1; x1 += ks2 + 1u;
  TFR(17) TFR(29) TFR(16) TFR(24)
  x0 += ks2; x1 += k0 + 2u;
  TFR(13) TFR(15) TFR(26) TFR(6)
  x0 += k0; x1 += k1 + 3u;
  TFR(17) TFR(29) TFR(16) TFR(24)
  x0 += k1; x1 += ks2 + 4u;
  TFR(13) TFR(15) TFR(26) TFR(6)
  x0 += ks2; x1 += k0 + 5u;
#undef TFR
  o0 = x0; o1 = x1;
}

__device__ __forceinline__ uint32_t tf_bits(uint32_t k0, uint32_t k1, uint32_t m)
{
#if JAX_PARTITIONABLE
  // 64-bit counter (hi=0, lo=m); 32-bit draw = o0 ^ o1
  uint32_t o0, o1;
  threefry2x32(k0, k1, 0u, m, o0, o1);
  return o0 ^ o1;
#else
  // original: counts=iota(N), split halves, concat(enc0, enc1)
  const uint32_t half = (BSZ * VOC) / 2;
  uint32_t o0, o1;
  if (m < half) { threefry2x32(k0, k1, m, m + half, o0, o1); return o0; }
  else          { threefry2x32(k0, k1, m - half, m, o0, o1); return o1; }
#endif
}

__device__ __forceinline__ float gumbel_from_bits(uint32_t bits)
{
  // JAX uniform: (bits>>9)|0x3F800000 bitcast - 1.0, clamped to tiny
  uint32_t fb = (bits >> 9) | 0x3F800000u;
  float u = __uint_as_float(fb) - 1.0f;
  u = fmaxf(u, 1.1754943508222875e-38f);
  return -logf(-logf(u));
}

__device__ __forceinline__ float sigmoidf(float v) { return 1.0f / (1.0f + expf(-v)); }

// ---------------------------------------------------------------- init
__global__ __launch_bounds__(256) void init_kernel(
    const float* __restrict__ encoded, float* __restrict__ h0,
    float* __restrict__ c, float* __restrict__ x,
    int* __restrict__ active, uint32_t* __restrict__ keys)
{
  int i = blockIdx.x * 256 + threadIdx.x;
  if (i < BSZ * HDIM) { h0[i] = 0.0f; c[i] = 0.0f; x[i] = encoded[i]; }
  if (blockIdx.x == 0) {
    int t = threadIdx.x;
    if (t < BSZ) active[t] = 1;
    if (t < SEQ) {
#if JAX_PARTITIONABLE
      uint32_t o0, o1;
      threefry2x32(0u, 42u, 0u, (uint32_t)t, o0, o1);
      keys[2 * t] = o0; keys[2 * t + 1] = o1;
#else
      uint32_t a0, a1, b0, b1;
      if (t < 24) {
        threefry2x32(0u, 42u, (uint32_t)(2 * t),     (uint32_t)(2 * t + 48), a0, a1);
        threefry2x32(0u, 42u, (uint32_t)(2 * t + 1), (uint32_t)(2 * t + 49), b0, b1);
        keys[2 * t] = a0; keys[2 * t + 1] = b0;
      } else {
        int i0 = 2 * t - 48, i1 = 2 * t - 47;
        threefry2x32(0u, 42u, (uint32_t)i0, (uint32_t)(i0 + 48), a0, a1);
        threefry2x32(0u, 42u, (uint32_t)i1, (uint32_t)(i1 + 48), b0, b1);
        keys[2 * t] = a1; keys[2 * t + 1] = b1;
      }
#endif
    }
  }
}

// ---------------------------------------------------------------- transpose
// dst[(c + cOff)*dstLD + r] = src[r*C + c]
__global__ void transpose_kernel(const float* __restrict__ src, float* __restrict__ dst,
                                 int R, int C, int dstLD, int cOff)
{
  __shared__ float tile[32][33];
  int cb = blockIdx.x * 32, rb = blockIdx.y * 32;
  int tx = threadIdx.x, ty = threadIdx.y;
  for (int j = ty; j < 32; j += 8) {
    int r = rb + j, cc = cb + tx;
    if (r < R && cc < C) tile[j][tx] = src[(size_t)r * C + cc];
  }
  __syncthreads();
  for (int j = ty; j < 32; j += 8) {
    int r = rb + tx, cc = cb + j;
    if (r < R && cc < C) dst[(size_t)(cc + cOff) * dstLD + r] = tile[tx][j];
  }
}

// ---------------------------------------------------------------- LSTM cell
// grid (32 jc, 8 bg), block 256 = (64 gate-lanes) x (4 k-quarters)
// gate lanes: 4 types (i,f,g,o) x 16 j within this jc slice; 4 batch per block
__global__ __launch_bounds__(256) void cell_kernel(
    const float* __restrict__ WT,   // [1024][2048] k-major combined Wi;Wh
    const float* __restrict__ bi, const float* __restrict__ bh,
    const float* __restrict__ x, const float* __restrict__ hin,
    float* __restrict__ hout, float* __restrict__ c)
{
  __shared__ float xh[KTOT * 4];     // [k][4b]
  __shared__ float red[4 * 64 * 4];  // [kq][gl][4b]
  __shared__ float gate[64 * 4];     // [(type*16+jj)][4b]
  int t = threadIdx.x;
  int jc = blockIdx.x;       // 0..31 -> j slice of 16
  int bg = blockIdx.y;       // 0..7  -> 4 batch
  int bbase = bg * 4;

  for (int i = 0; i < 16; ++i) {
    int idx = i * 256 + t;               // 4096 = 1024k x 4b
    int b = idx >> 10, k = idx & 1023;
    float v = (k < EDIM) ? x[(bbase + b) * EDIM + k]
                         : hin[(bbase + b) * HDIM + (k - EDIM)];
    xh[k * 4 + b] = v;
  }
  __syncthreads();

  int gl = t & 63, kq = t >> 6;
  int type = gl >> 4, jj = gl & 15;
  int gcol = type * 512 + jc * 16 + jj;
  float acc0 = 0.f, acc1 = 0.f, acc2 = 0.f, acc3 = 0.f;
  const float* wp = WT + (size_t)(kq * 256) * GDIM + gcol;
  const float4* xp = (const float4*)xh + kq * 256;
#pragma unroll 8
  for (int k = 0; k < 256; ++k) {
    float w = wp[(size_t)k * GDIM];
    float4 h4 = xp[k];
    acc0 += w * h4.x; acc1 += w * h4.y; acc2 += w * h4.z; acc3 += w * h4.w;
  }
  ((float4*)red)[t] = make_float4(acc0, acc1, acc2, acc3);
  __syncthreads();

  if (t < 64) {
    float4 s0 = ((float4*)red)[t];
    float4 s1 = ((float4*)red)[64 + t];
    float4 s2 = ((float4*)red)[128 + t];
    float4 s3 = ((float4*)red)[192 + t];
    int ty2 = t >> 4, jj2 = t & 15;
    int gc2 = ty2 * 512 + jc * 16 + jj2;
    float bsum = bi[gc2] + bh[gc2];
    float4 g;
    g.x = s0.x + s1.x + s2.x + s3.x + bsum;
    g.y = s0.y + s1.y + s2.y + s3.y + bsum;
    g.z = s0.z + s1.z + s2.z + s3.z + bsum;
    g.w = s0.w + s1.w + s2.w + s3.w + bsum;
    ((float4*)gate)[t] = g;
  }
  __syncthreads();

  if (t < 64) {
    int b = t >> 4, jjf = t & 15;
    float ig = sigmoidf(gate[(0 * 16 + jjf) * 4 + b]);
    float fg = sigmoidf(gate[(1 * 16 + jjf) * 4 + b]);
    float gg = tanhf(  gate[(2 * 16 + jjf) * 4 + b]);
    float og = sigmoidf(gate[(3 * 16 + jjf) * 4 + b]);
    int ci = (bbase + b) * HDIM + jc * 16 + jjf;
    float cn = fg * c[ci] + ig * gg;
    c[ci] = cn;
    hout[ci] = og * tanhf(cn);
  }
}

// ---------------------------------------------------------------- logits
// grid 250 blocks x 128 vocab, block 256 = (64 vl) x (4 kq); 2 vocab/thread.
// Writes raw logits into d_out[b][s][v]; per-block partials for max/sumexp
// and gumbel-argmax.
__global__ __launch_bounds__(256) void logits_kernel(
    const float* __restrict__ WoT,  // [512][32000]
    const float* __restrict__ bo,
    const float* __restrict__ h,    // [32][512]
    const uint32_t* __restrict__ keys, int step,
    float* __restrict__ out,
    float* __restrict__ pmax, float* __restrict__ psum,
    float* __restrict__ pgv, int* __restrict__ pgi)
{
  __shared__ float smem[16384];   // 64KB: h-stage [512][32] -> red [32][4*128] -> L [32][128]
  int t = threadIdx.x, bid = blockIdx.x;
  int v0 = bid * 128;
  int vl = t & 63, kq = t >> 6;

  { // stage h transposed to [k][b]; float4 global reads, conflict-free LDS writes
    const float4* hp4 = (const float4*)h;
#pragma unroll
    for (int i = 0; i < 16; ++i) {
      int idx4 = i * 256 + t;            // 4096 = 32b x 128 k4
      int b = idx4 & 31, k4 = idx4 >> 5;
      float4 v = hp4[b * 128 + k4];
      smem[(k4 * 4 + 0) * 32 + b] = v.x;
      smem[(k4 * 4 + 1) * 32 + b] = v.y;
      smem[(k4 * 4 + 2) * 32 + b] = v.z;
      smem[(k4 * 4 + 3) * 32 + b] = v.w;
    }
  }
  __syncthreads();

  float acc0[32], acc1[32];
#pragma unroll
  for (int b = 0; b < 32; ++b) { acc0[b] = 0.f; acc1[b] = 0.f; }
  const int va = v0 + vl, vb = va + 64;
#pragma unroll 4
  for (int kk = 0; kk < 128; ++kk) {
    int k = kq * 128 + kk;
    float w0 = WoT[(size_t)k * VOC + va];
    float w1 = WoT[(size_t)k * VOC + vb];
    const float4* hp = (const float4*)(smem + k * 32);
#pragma unroll
    for (int bq = 0; bq < 8; ++bq) {
      float4 h4 = hp[bq];
      acc0[bq * 4 + 0] += w0 * h4.x; acc1[bq * 4 + 0] += w1 * h4.x;
      acc0[bq * 4 + 1] += w0 * h4.y; acc1[bq * 4 + 1] += w1 * h4.y;
      acc0[bq * 4 + 2] += w0 * h4.z; acc1[bq * 4 + 2] += w1 * h4.z;
      acc0[bq * 4 + 3] += w0 * h4.w; acc1[bq * 4 + 3] += w1 * h4.w;
    }
  }
  __syncthreads();   // h-stage dead; reuse smem as red[32][4*128]
#pragma unroll
  for (int b = 0; b < 32; ++b) smem[b * 512 + kq * 128 + vl]      = acc0[b];
#pragma unroll
  for (int b = 0; b < 32; ++b) smem[b * 512 + kq * 128 + 64 + vl] = acc1[b];
  __syncthreads();

  float lg[16];
#pragma unroll
  for (int rep = 0; rep < 16; ++rep) {
    int i = rep * 256 + t;               // 4096 = 32b x 128 vl2
    int b = i >> 7, vl2 = i & 127;
    float s = smem[b * 512 + 0 * 128 + vl2] + smem[b * 512 + 1 * 128 + vl2]
            + smem[b * 512 + 2 * 128 + vl2] + smem[b * 512 + 3 * 128 + vl2];
    float logit = s + bo[v0 + vl2];
    out[(size_t)b * (SEQ * VOC) + (size_t)step * VOC + v0 + vl2] = logit;
    lg[rep] = logit;
  }
  __syncthreads();   // red dead; reuse smem as L[32][128]
#pragma unroll
  for (int rep = 0; rep < 16; ++rep) {
    int i = rep * 256 + t;
    int b = i >> 7, vl2 = i & 127;
    smem[b * 128 + vl2] = lg[rep];
  }
  __syncthreads();

  // per-b partial reductions over this block's 128 vocab; 8 lanes per b
  int b = t >> 3, l = t & 7;
  float m = -INFINITY;
#pragma unroll
  for (int j = 0; j < 16; ++j) m = fmaxf(m, smem[b * 128 + l + j * 8]);
#pragma unroll
  for (int d = 1; d < 8; d <<= 1) m = fmaxf(m, __shfl_xor(m, d, 64));

  uint32_t k0 = keys[2 * step], k1 = keys[2 * step + 1];
  float ssum = 0.f, gv = -INFINITY;
  int gi = INT_MAX;
#pragma unroll 4
  for (int j = 0; j < 16; ++j) {
    int vl2 = l + j * 8;
    float logit = smem[b * 128 + vl2];
    ssum += expf(logit - m);
    int vg = v0 + vl2;
    uint32_t bits = tf_bits(k0, k1, (uint32_t)(b * VOC + vg));
    float val = logit + gumbel_from_bits(bits);
    if (val > gv || (val == gv && vg < gi)) { gv = val; gi = vg; }
  }
#pragma unroll
  for (int d = 1; d < 8; d <<= 1) {
    ssum += __shfl_xor(ssum, d, 64);
    float ogv = __shfl_xor(gv, d, 64);
    int   ogi = __shfl_xor(gi, d, 64);
    if (ogv > gv || (ogv == gv && ogi < gi)) { gv = ogv; gi = ogi; }
  }
  if (l == 0) {
    pmax[bid * 32 + b] = m;
    psum[bid * 32 + b] = ssum;
    pgv[bid * 32 + b]  = gv;
    pgi[bid * 32 + b]  = gi;
  }
}

// ---------------------------------------------------------------- finalize
// grid 32 (one per batch row): combine 250 partials -> lse, sampled token,
// EOS latch, embed next input.
__global__ __launch_bounds__(256) void final_kernel(
    const float* __restrict__ pmax, const float* __restrict__ psum,
    const float* __restrict__ pgv, const int* __restrict__ pgi,
    const float* __restrict__ emb, float* __restrict__ x,
    float* __restrict__ lse_s, int* __restrict__ act_s, int* __restrict__ active,
    int step, int nblk)
{
  __shared__ float sm[256], ss[256], sv[256];
  __shared__ int si[256];
  __shared__ int toksh;
  int b = blockIdx.x, t = threadIdx.x;
  float m = -INFINITY, s = 0.f, gv = -INFINITY;
  int gi = INT_MAX;
  if (t < nblk) {
    m = pmax[t * 32 + b]; s = psum[t * 32 + b];
    gv = pgv[t * 32 + b]; gi = pgi[t * 32 + b];
  }
  sm[t] = m; __syncthreads();
  for (int st = 128; st > 0; st >>= 1) {
    if (t < st) sm[t] = fmaxf(sm[t], sm[t + st]);
    __syncthreads();
  }
  float M = sm[0];
  ss[t] = (t < nblk) ? s * expf(m - M) : 0.f;
  sv[t] = gv; si[t] = gi;
  __syncthreads();
  for (int st = 128; st > 0; st >>= 1) {
    if (t < st) {
      ss[t] += ss[t + st];
      if (sv[t + st] > sv[t] || (sv[t + st] == sv[t] && si[t + st] < si[t])) {
        sv[t] = sv[t + st]; si[t] = si[t + st];
      }
    }
    __syncthreads();
  }
  if (t == 0) {
    lse_s[step * 32 + b] = M + logf(ss[0]);
    int tok = si[0];
    act_s[step * 32 + b] = active[b];   // mask uses active ENTERING the step
    if (tok == EOS_TOK) active[b] = 0;
    toksh = tok;
  }
  __syncthreads();
  int tok = toksh;
  for (int i = t; i < EDIM; i += 256) x[b * EDIM + i] = emb[(size_t)tok * EDIM + i];
}

// ---------------------------------------------------------------- epilogue
// out[b][s][v] = act ? raw_logit - lse : 0
__global__ __launch_bounds__(256) void finish_kernel(
    float4* __restrict__ out4, const float* __restrict__ lse_s,
    const int* __restrict__ act_s)
{
  const int N4 = BSZ * SEQ * VOC / 4;          // 12,288,000
  for (int f = blockIdx.x * 256 + threadIdx.x; f < N4; f += gridDim.x * 256) {
    int row = f / (VOC / 4);                   // b*48 + s
    int b = row / SEQ, s = row - b * SEQ;
    int idx = s * 32 + b;
    float4 v = out4[f];
    if (act_s[idx]) {
      float l = lse_s[idx];
      v.x -= l; v.y -= l; v.z -= l; v.w -= l;
    } else {
      v.x = 0.f; v.y = 0.f; v.z = 0.f; v.w = 0.f;
    }
    out4[f] = v;
  }
}

// ---------------------------------------------------------------- launch
extern "C" void kernel_launch(void* const* d_in, const int* in_sizes, int n_in,
                              void* d_out, int out_size, void* d_ws, size_t ws_size,
                              hipStream_t stream)
{
  (void)in_sizes; (void)n_in; (void)out_size; (void)ws_size;
  const float* encoded = (const float*)d_in[0];
  const float* emb     = (const float*)d_in[1];
  const float* Wi      = (const float*)d_in[2];
  const float* Wh      = (const float*)d_in[3];
  const float* bi      = (const float*)d_in[4];
  const float* bh      = (const float*)d_in[5];
  const float* Wo      = (const float*)d_in[6];
  const float* bo      = (const float*)d_in[7];
  float* out = (float*)d_out;

  float* ws   = (float*)d_ws;
  float* WT   = ws;                        // [1024][2048]
  float* WoT  = WT + (size_t)KTOT * GDIM;  // [512][32000]
  float* h0   = WoT + (size_t)HDIM * VOC;
  float* h1   = h0 + BSZ * HDIM;
  float* c    = h1 + BSZ * HDIM;
  float* x    = c + BSZ * HDIM;
  float* pmax = x + BSZ * EDIM;            // [250][32]
  float* psum = pmax + 250 * 32;
  float* pgv  = psum + 250 * 32;
  int*   pgi  = (int*)(pgv + 250 * 32);
  float* lse_s = (float*)(pgi + 250 * 32); // [48][32]
  int*   act_s = (int*)(lse_s + SEQ * BSZ);
  int*   active = act_s + SEQ * BSZ;
  uint32_t* keys = (uint32_t*)(active + BSZ);

  init_kernel<<<dim3(64), dim3(256), 0, stream>>>(encoded, h0, c, x, active, keys);
  transpose_kernel<<<dim3(16, 64),   dim3(32, 8), 0, stream>>>(Wi, WT, GDIM, EDIM, GDIM, 0);
  transpose_kernel<<<dim3(16, 64),   dim3(32, 8), 0, stream>>>(Wh, WT, GDIM, HDIM, GDIM, 512);
  transpose_kernel<<<dim3(16, 1000), dim3(32, 8), 0, stream>>>(Wo, WoT, VOC, HDIM, VOC, 0);

  for (int s = 0; s < SEQ; ++s) {
    float* hin  = (s & 1) ? h1 : h0;
    float* hout = (s & 1) ? h0 : h1;
    cell_kernel<<<dim3(32, 8), dim3(256), 0, stream>>>(WT, bi, bh, x, hin, hout, c);
    logits_kernel<<<dim3(250), dim3(256), 0, stream>>>(WoT, bo, hout, keys, s, out,
                                                       pmax, psum, pgv, pgi);
    final_kernel<<<dim3(32), dim3(256), 0, stream>>>(pmax, psum, pgv, pgi, emb, x,
                                                     lse_s, act_s, active, s, 250);
  }
  finish_kernel<<<dim3(2048), dim3(256), 0, stream>>>((float4*)out, lse_s, act_s);
}